// Round 5
// baseline (188.785 us; speedup 1.0000x reference)
//
#include <hip/hip_runtime.h>
#include <hip/hip_bf16.h>
#include <cstdint>
#include <cstddef>

#define NA   2048
#define NB   2048
#define DD   512

typedef __attribute__((ext_vector_type(8))) short bf16x8;
typedef __attribute__((ext_vector_type(4))) float f32x4;
typedef unsigned short u16;
typedef unsigned int   u32;

__device__ __forceinline__ u16 f2b_hw(float f) {
    u32 w;
    asm("v_cvt_pk_bf16_f32 %0, %1, %2" : "=v"(w) : "v"(f), "v"(f));
    return (u16)w;
}
__device__ __forceinline__ float b2f(u16 h) {
    return __uint_as_float(((u32)h) << 16);
}
__device__ __forceinline__ u32 umin32(u32 a, u32 b) { return a < b ? a : b; }
__device__ __forceinline__ u32 umax32(u32 a, u32 b) { return a > b ? a : b; }
__device__ __forceinline__ u32 med3u(u32 a, u32 b, u32 c) {
    return umax32(umin32(a, b), umin32(umax32(a, b), c));   // -> v_med3_u32
}
__device__ __forceinline__ bf16x8 cvt8(f32x4 v0, f32x4 v1) {
    u32 w0, w1, w2, w3;
    asm("v_cvt_pk_bf16_f32 %0, %1, %2" : "=v"(w0) : "v"(v0[0]), "v"(v0[1]));
    asm("v_cvt_pk_bf16_f32 %0, %1, %2" : "=v"(w1) : "v"(v0[2]), "v"(v0[3]));
    asm("v_cvt_pk_bf16_f32 %0, %1, %2" : "=v"(w2) : "v"(v1[0]), "v"(v1[1]));
    asm("v_cvt_pk_bf16_f32 %0, %1, %2" : "=v"(w3) : "v"(v1[2]), "v"(v1[3]));
    union { u32 u[4]; bf16x8 v; } cv;
    cv.u[0] = w0; cv.u[1] = w1; cv.u[2] = w2; cv.u[3] = w3;
    return cv.v;
}

#define GLDS16(gsrc, ldst)                                                  \
    __builtin_amdgcn_global_load_lds(                                       \
        (const __attribute__((address_space(1))) void*)(gsrc),              \
        (__attribute__((address_space(3))) void*)(ldst), 16, 0, 0)

// ---------------------------------------------------------------------------
// Coalesced LDS-transpose: W2T[n][k]=W[512+k][n], WdT[n][k]=W[k][n]-W[512+k][n]
// ---------------------------------------------------------------------------
__global__ __launch_bounds__(256) void prep_w(const float* __restrict__ W,
                                              u16* __restrict__ W2T,
                                              u16* __restrict__ WdT) {
    __shared__ float s2[64][65];
    __shared__ float sd[64][65];
    int kb = blockIdx.x * 64, nb = blockIdx.y * 64;
    int tid = threadIdx.x;
    int c = tid & 63, r0 = tid >> 6;
    #pragma unroll
    for (int p = 0; p < 16; ++p) {
        int r = p * 4 + r0;
        float w1 = W[(size_t)(kb + r) * DD + nb + c];
        float w2 = W[(size_t)(512 + kb + r) * DD + nb + c];
        s2[r][c] = w2;
        sd[r][c] = w1 - w2;
    }
    __syncthreads();
    #pragma unroll
    for (int p = 0; p < 16; ++p) {
        int n = p * 4 + r0;
        W2T[(size_t)(nb + n) * DD + kb + c] = f2b_hw(s2[c][n]);
        WdT[(size_t)(nb + n) * DD + kb + c] = f2b_hw(sd[c][n]);
    }
}

// ---------------------------------------------------------------------------
// Exact integer top-4 NN (lax.top_k tie-break). key=(s<<11)|j.
// ---------------------------------------------------------------------------
__global__ __launch_bounds__(512) void topk_kernel(const int* __restrict__ ca,
                                                   const int* __restrict__ cb,
                                                   int* __restrict__ idx_out,
                                                   float* __restrict__ w_out) {
    __shared__ u32 pcb[NB];
    __shared__ u32 part[3 * 128 * 4];
    int b = blockIdx.y;
    int tid = threadIdx.x;
    for (int p = tid; p < NB; p += 512) {
        const int* c = cb + ((size_t)b * NB + p) * 3;
        pcb[p] = (u32)c[0] | ((u32)c[1] << 8) | ((u32)c[2] << 16);
    }
    __syncthreads();

    int q = tid & 127, g = tid >> 7;
    int i = blockIdx.x * 128 + q;
    const int* ac = ca + ((size_t)b * NA + i) * 3;
    int ax = ac[0], ay = ac[1], az = ac[2];

    u32 k0 = ~0u, k1 = ~0u, k2 = ~0u, k3 = ~0u;
    int j0 = g * 512;
    #pragma unroll 8
    for (int jj = 0; jj < 512; ++jj) {
        int j = j0 + jj;
        u32 p = pcb[j];
        int dx = ax - (int)(p & 255u);
        int dy = ay - (int)((p >> 8) & 255u);
        int dz = az - (int)(p >> 16);
        u32 s = (u32)(__mul24(dx, dx) + __mul24(dy, dy) + __mul24(dz, dz));
        u32 key = (s << 11) | (u32)j;
        u32 nk0 = umin32(k0, key);
        u32 nk1 = med3u(key, k0, k1);
        u32 nk2 = med3u(key, k1, k2);
        u32 nk3 = med3u(key, k2, k3);
        k0 = nk0; k1 = nk1; k2 = nk2; k3 = nk3;
    }
    if (g) {
        u32* pp = &part[((g - 1) * 128 + q) * 4];
        pp[0] = k0; pp[1] = k1; pp[2] = k2; pp[3] = k3;
    }
    __syncthreads();
    if (g == 0) {
        #pragma unroll
        for (int L = 0; L < 3; ++L) {
            const u32* pp = &part[(L * 128 + q) * 4];
            #pragma unroll
            for (int t = 0; t < 4; ++t) {
                u32 key = pp[t];
                u32 nk0 = umin32(k0, key);
                u32 nk1 = med3u(key, k0, k1);
                u32 nk2 = med3u(key, k1, k2);
                u32 nk3 = med3u(key, k2, k3);
                k0 = nk0; k1 = nk1; k2 = nk2; k3 = nk3;
            }
        }
        size_t o = ((size_t)b * NA + i) * 4;
        u32 ks[4] = {k0, k1, k2, k3};
        #pragma unroll
        for (int t = 0; t < 4; ++t) {
            idx_out[o + t] = (int)(ks[t] & 2047u);
            float d = sqrtf((float)(ks[t] >> 11)) * (1.0f / 128.0f);
            w_out[o + t] = 0.5f - fminf(d, 0.5f);
        }
    }
}

// ---------------------------------------------------------------------------
// C = A(f32) @ BT^T(bf16). Block = 64 rows x 512 cols, 4 waves (64m x 128n).
// A: global->reg (L1-served wave reuse), cvt_pk in reg. Never in LDS.
// B: [512][32] bf16 per K-step via GLDS16, double-buffered, slot-XOR swizzle.
// Pipeline: counted vmcnt(12), 2 barriers/K-step.
// FUSED: wave0 copies A f32 tile to out[:,0:512]; gather epilogue for
//        out[:,512:1024] (Ps in LDS reusing B buffers).
// ---------------------------------------------------------------------------
template<bool FUSED>
__global__ __launch_bounds__(256, 2) void gemm_kernel(
    const float* __restrict__ A, const u16* __restrict__ BT,
    u16* __restrict__ C, const int* __restrict__ idxb,
    const float* __restrict__ wb, const float* __restrict__ bias,
    const u16* __restrict__ Qb, float* __restrict__ out) {

    __shared__ __align__(16) char smem[FUSED ? 66560 : 65536];

    const int tid  = threadIdx.x;
    const int lane = tid & 63;
    const int wave = tid >> 6;
    const int bid  = blockIdx.x;
    const int swz  = ((bid & 7) << 6) | (bid >> 3);   // bijective 8x64
    const int m0   = swz << 6;                        // 64 rows per block
    const int l15  = lane & 15;
    const int lk8  = (lane >> 4) << 3;                // 0,8,16,24
    const int qp   = lane >> 4;                       // frag piece index
    const int wc   = wave << 7;                       // wave n-offset

    // B staging source: call c stages rows wc+c*16 .. +15 (this wave's n-range)
    const int sp = (lane & 3) ^ ((lane >> 3) & 3);    // pre-swizzled piece
    const u16* bsrc0 = BT + (size_t)(wc + (lane >> 2)) * DD + sp * 8;

    // A row pointers (4 m-frags)
    const float* arow[4];
    #pragma unroll
    for (int mf = 0; mf < 4; ++mf)
        arow[mf] = A + (size_t)(m0 + mf * 16 + l15) * DD + lk8;

    // B frag LDS byte offsets (swizzled read)
    int boff[8];
    #pragma unroll
    for (int nf = 0; nf < 8; ++nf) {
        int R = wc + nf * 16 + l15;
        boff[nf] = R * 64 + ((qp ^ ((R >> 1) & 3)) << 4);
    }

    f32x4 acc[4][8];
    #pragma unroll
    for (int mf = 0; mf < 4; ++mf)
        #pragma unroll
        for (int nf = 0; nf < 8; ++nf)
            acc[mf][nf] = (f32x4){0.f, 0.f, 0.f, 0.f};

    f32x4 ap[8];
    bf16x8 afA[4], afB[4];

#define AISSUE(kk)                                                           \
    { _Pragma("unroll") for (int mf = 0; mf < 4; ++mf) {                     \
        ap[2*mf]   = *(const f32x4*)(arow[mf] + (kk));                       \
        ap[2*mf+1] = *(const f32x4*)(arow[mf] + (kk) + 4); } }

#define GISSUE(kk, bufb)                                                     \
    { _Pragma("unroll") for (int c = 0; c < 8; ++c)                          \
        GLDS16(bsrc0 + c * (16 * DD) + (kk),                                 \
               smem + (bufb) + (wave << 13) + (c << 10)); }

#define ACVT(af, kk)                                                         \
    { _Pragma("unroll") for (int mf = 0; mf < 4; ++mf) {                     \
        if (FUSED && wave == 0) {                                            \
            float* op_ = out + (size_t)(m0 + mf*16 + l15) * 1024 + (kk)+lk8; \
            *(f32x4*)op_       = ap[2*mf];                                   \
            *(f32x4*)(op_ + 4) = ap[2*mf+1];                                 \
        }                                                                    \
        af[mf] = cvt8(ap[2*mf], ap[2*mf+1]); } }

#define MFMAS(af, bufb)                                                      \
    { _Pragma("unroll") for (int nf = 0; nf < 8; ++nf) {                     \
        bf16x8 bv_ = *(const bf16x8*)(smem + (bufb) + boff[nf]);             \
        _Pragma("unroll") for (int mf = 0; mf < 4; ++mf)                     \
            acc[mf][nf] = __builtin_amdgcn_mfma_f32_16x16x32_bf16(           \
                af[mf], bv_, acc[mf][nf], 0, 0, 0); } }

    AISSUE(0); GISSUE(0, 0);
    ACVT(afA, 0);                       // compiler waits only the 8 A-loads

    #pragma unroll 1
    for (int t2 = 0; t2 < 8; ++t2) {
        const int kk = t2 * 64;
        // even step: consume buf0/afA, prefetch kk+32 into buf1
        AISSUE(kk + 32); GISSUE(kk + 32, 32768);
        asm volatile("s_waitcnt vmcnt(12)" ::: "memory");
        __builtin_amdgcn_s_barrier();
        MFMAS(afA, 0);
        ACVT(afB, kk + 32);
        asm volatile("" ::: "memory");
        __builtin_amdgcn_s_barrier();
        // odd step: consume buf1/afB, prefetch kk+64 into buf0
        if (t2 < 7) {
            AISSUE(kk + 64); GISSUE(kk + 64, 0);
            asm volatile("s_waitcnt vmcnt(12)" ::: "memory");
        } else {
            asm volatile("s_waitcnt vmcnt(0)" ::: "memory");
        }
        __builtin_amdgcn_s_barrier();
        MFMAS(afB, 32768);
        if (t2 < 7) { ACVT(afA, kk + 64); }
        asm volatile("" ::: "memory");
        __builtin_amdgcn_s_barrier();
    }

    const int r4 = (lane >> 4) * 4;

    if (!FUSED) {
        #pragma unroll
        for (int mf = 0; mf < 4; ++mf)
            #pragma unroll
            for (int nf = 0; nf < 8; ++nf)
                #pragma unroll
                for (int j = 0; j < 4; ++j) {
                    int row = m0 + mf * 16 + r4 + j;
                    int col = wc + nf * 16 + l15;
                    C[(size_t)row * DD + col] = f2b_hw(acc[mf][nf][j]);
                }
        return;
    }

    // ---- fused epilogue ----
    float bi[8];
    #pragma unroll
    for (int nf = 0; nf < 8; ++nf)
        bi[nf] = bias[wc + nf * 16 + l15];

    u16* Ps = (u16*)smem;               // [64][520] bf16, 66560 B
    #pragma unroll
    for (int mf = 0; mf < 4; ++mf)
        #pragma unroll
        for (int nf = 0; nf < 8; ++nf)
            #pragma unroll
            for (int j = 0; j < 4; ++j)
                Ps[(mf * 16 + r4 + j) * 520 + wc + nf * 16 + l15] =
                    f2b_hw(acc[mf][nf][j] + bi[nf]);
    __syncthreads();

    const int l16 = tid & 15;
    const u16* qs = Qb + ((size_t)(swz >> 5) << 20);   // batch * 2048 * 512
    #pragma unroll
    for (int rr = 0; rr < 4; ++rr) {
        const int row = (tid >> 4) * 4 + rr;
        const int gr  = m0 + row;
        int4  iv = *(const int4*)(idxb + (size_t)gr * 4);
        f32x4 wv = *(const f32x4*)(wb + (size_t)gr * 4);
        #pragma unroll
        for (int cc = 0; cc < 4; ++cc) {
            const int col = cc * 128 + l16 * 8;
            bf16x8 p8 = *(const bf16x8*)(Ps + row * 520 + col);
            bf16x8 q0 = *(const bf16x8*)(qs + (size_t)iv.x * DD + col);
            bf16x8 q1 = *(const bf16x8*)(qs + (size_t)iv.y * DD + col);
            bf16x8 q2 = *(const bf16x8*)(qs + (size_t)iv.z * DD + col);
            bf16x8 q3 = *(const bf16x8*)(qs + (size_t)iv.w * DD + col);
            float o[8];
            #pragma unroll
            for (int j = 0; j < 8; ++j) {
                float p = b2f((u16)p8[j]);
                float s;
                s  = fmaxf(p + b2f((u16)q0[j]), 0.f) * wv[0];
                s += fmaxf(p + b2f((u16)q1[j]), 0.f) * wv[1];
                s += fmaxf(p + b2f((u16)q2[j]), 0.f) * wv[2];
                s += fmaxf(p + b2f((u16)q3[j]), 0.f) * wv[3];
                o[j] = s;
            }
            float* op = out + (size_t)gr * 1024 + 512 + col;
            *(f32x4*)op       = (f32x4){o[0], o[1], o[2], o[3]};
            *(f32x4*)(op + 4) = (f32x4){o[4], o[5], o[6], o[7]};
        }
    }
}

extern "C" void kernel_launch(void* const* d_in, const int* in_sizes, int n_in,
                              void* d_out, int out_size, void* d_ws, size_t ws_size,
                              hipStream_t stream) {
    const float* fa   = (const float*)d_in[0];
    const float* fb   = (const float*)d_in[1];
    const float* W    = (const float*)d_in[2];
    const float* bias = (const float*)d_in[3];
    const int*   ca   = (const int*)d_in[4];
    const int*   cb   = (const int*)d_in[5];
    float* out = (float*)d_out;

    char* ws = (char*)d_ws;
    u16*   Qb   = (u16*)(ws);                       // 32 MB bf16 Q
    u16*   W2T  = (u16*)(ws + 33554432);            // 512 KB
    u16*   WdT  = (u16*)(ws + 34078720);            // 512 KB
    int*   idxb = (int*)(ws + 34603008);            // 512 KB
    float* wb   = (float*)(ws + 35127296);          // 512 KB

    dim3 pg(8, 8);
    prep_w<<<pg, 256, 0, stream>>>(W, W2T, WdT);

    dim3 tg(16, 16);
    topk_kernel<<<tg, 512, 0, stream>>>(ca, cb, idxb, wb);

    gemm_kernel<false><<<512, 256, 0, stream>>>(fb, WdT, Qb, nullptr, nullptr,
                                                nullptr, nullptr, nullptr);
    gemm_kernel<true><<<512, 256, 0, stream>>>(fa, W2T, nullptr, idxb, wb,
                                               bias, Qb, out);
}

// Round 6
// 180.647 us; speedup vs baseline: 1.0450x; 1.0450x over previous
//
#include <hip/hip_runtime.h>
#include <hip/hip_bf16.h>
#include <cstdint>
#include <cstddef>

#define NA   2048
#define NB   2048
#define DD   512

typedef __attribute__((ext_vector_type(8))) short bf16x8;
typedef __attribute__((ext_vector_type(4))) float f32x4;
typedef unsigned short u16;
typedef unsigned int   u32;

__device__ __forceinline__ u16 f2b_hw(float f) {
    u32 w;
    asm("v_cvt_pk_bf16_f32 %0, %1, %2" : "=v"(w) : "v"(f), "v"(f));
    return (u16)w;
}
__device__ __forceinline__ float b2f(u16 h) {
    return __uint_as_float(((u32)h) << 16);
}
__device__ __forceinline__ u32 umin32(u32 a, u32 b) { return a < b ? a : b; }
__device__ __forceinline__ u32 umax32(u32 a, u32 b) { return a > b ? a : b; }
__device__ __forceinline__ u32 med3u(u32 a, u32 b, u32 c) {
    return umax32(umin32(a, b), umin32(umax32(a, b), c));   // -> v_med3_u32
}
__device__ __forceinline__ bf16x8 cvt8(f32x4 v0, f32x4 v1) {
    u32 w0, w1, w2, w3;
    asm("v_cvt_pk_bf16_f32 %0, %1, %2" : "=v"(w0) : "v"(v0[0]), "v"(v0[1]));
    asm("v_cvt_pk_bf16_f32 %0, %1, %2" : "=v"(w1) : "v"(v0[2]), "v"(v0[3]));
    asm("v_cvt_pk_bf16_f32 %0, %1, %2" : "=v"(w2) : "v"(v1[0]), "v"(v1[1]));
    asm("v_cvt_pk_bf16_f32 %0, %1, %2" : "=v"(w3) : "v"(v1[2]), "v"(v1[3]));
    union { u32 u[4]; bf16x8 v; } cv;
    cv.u[0] = w0; cv.u[1] = w1; cv.u[2] = w2; cv.u[3] = w3;
    return cv.v;
}

#define GLDS16(gsrc, ldst)                                                  \
    __builtin_amdgcn_global_load_lds(                                       \
        (const __attribute__((address_space(1))) void*)(gsrc),              \
        (__attribute__((address_space(3))) void*)(ldst), 16, 0, 0)

// ---------------------------------------------------------------------------
// Coalesced LDS-transpose: W2T[n][k]=W[512+k][n], WdT[n][k]=W[k][n]-W[512+k][n]
// ---------------------------------------------------------------------------
__global__ __launch_bounds__(256) void prep_w(const float* __restrict__ W,
                                              u16* __restrict__ W2T,
                                              u16* __restrict__ WdT) {
    __shared__ float s2[64][65];
    __shared__ float sd[64][65];
    int kb = blockIdx.x * 64, nb = blockIdx.y * 64;
    int tid = threadIdx.x;
    int c = tid & 63, r0 = tid >> 6;
    #pragma unroll
    for (int p = 0; p < 16; ++p) {
        int r = p * 4 + r0;
        float w1 = W[(size_t)(kb + r) * DD + nb + c];
        float w2 = W[(size_t)(512 + kb + r) * DD + nb + c];
        s2[r][c] = w2;
        sd[r][c] = w1 - w2;
    }
    __syncthreads();
    #pragma unroll
    for (int p = 0; p < 16; ++p) {
        int n = p * 4 + r0;
        W2T[(size_t)(nb + n) * DD + kb + c] = f2b_hw(s2[c][n]);
        WdT[(size_t)(nb + n) * DD + kb + c] = f2b_hw(sd[c][n]);
    }
}

// ---------------------------------------------------------------------------
// Exact integer top-4 NN (lax.top_k tie-break)  +  streaming conversions:
// fa -> out[:,0:512] (f32) and Ab (bf16);  fb -> Bb (bf16).
// Memory traffic rides under / after the VALU-bound distance loop.
// ---------------------------------------------------------------------------
__global__ __launch_bounds__(512) void topk_kernel(const int* __restrict__ ca,
                                                   const int* __restrict__ cb,
                                                   int* __restrict__ idx_out,
                                                   float* __restrict__ w_out,
                                                   const float* __restrict__ fa,
                                                   const float* __restrict__ fb,
                                                   u16* __restrict__ Ab,
                                                   u16* __restrict__ Bb,
                                                   float* __restrict__ out) {
    __shared__ u32 pcb[NB];
    __shared__ u32 part[3 * 128 * 4];
    int b = blockIdx.y;
    int tid = threadIdx.x;
    for (int p = tid; p < NB; p += 512) {
        const int* c = cb + ((size_t)b * NB + p) * 3;
        pcb[p] = (u32)c[0] | ((u32)c[1] << 8) | ((u32)c[2] << 16);
    }
    __syncthreads();

    int q = tid & 127, g = tid >> 7;
    int i = blockIdx.x * 128 + q;
    const int* ac = ca + ((size_t)b * NA + i) * 3;
    int ax = ac[0], ay = ac[1], az = ac[2];

    u32 k0 = ~0u, k1 = ~0u, k2 = ~0u, k3 = ~0u;
    int j0 = g * 512;
    #pragma unroll 8
    for (int jj = 0; jj < 512; ++jj) {
        int j = j0 + jj;
        u32 p = pcb[j];
        int dx = ax - (int)(p & 255u);
        int dy = ay - (int)((p >> 8) & 255u);
        int dz = az - (int)(p >> 16);
        u32 s = (u32)(__mul24(dx, dx) + __mul24(dy, dy) + __mul24(dz, dz));
        u32 key = (s << 11) | (u32)j;
        u32 nk0 = umin32(k0, key);
        u32 nk1 = med3u(key, k0, k1);
        u32 nk2 = med3u(key, k1, k2);
        u32 nk3 = med3u(key, k2, k3);
        k0 = nk0; k1 = nk1; k2 = nk2; k3 = nk3;
    }
    if (g) {
        u32* pp = &part[((g - 1) * 128 + q) * 4];
        pp[0] = k0; pp[1] = k1; pp[2] = k2; pp[3] = k3;
    }
    __syncthreads();
    if (g == 0) {
        #pragma unroll
        for (int L = 0; L < 3; ++L) {
            const u32* pp = &part[(L * 128 + q) * 4];
            #pragma unroll
            for (int t = 0; t < 4; ++t) {
                u32 key = pp[t];
                u32 nk0 = umin32(k0, key);
                u32 nk1 = med3u(key, k0, k1);
                u32 nk2 = med3u(key, k1, k2);
                u32 nk3 = med3u(key, k2, k3);
                k0 = nk0; k1 = nk1; k2 = nk2; k3 = nk3;
            }
        }
        size_t o = ((size_t)b * NA + i) * 4;
        u32 ks[4] = {k0, k1, k2, k3};
        #pragma unroll
        for (int t = 0; t < 4; ++t) {
            idx_out[o + t] = (int)(ks[t] & 2047u);
            float d = sqrtf((float)(ks[t] >> 11)) * (1.0f / 128.0f);
            w_out[o + t] = 0.5f - fminf(d, 0.5f);
        }
    }

    // ---- streaming copy/convert: this block owns 128 rows (cid*128..) ----
    const int cid = b * 16 + blockIdx.x;
    {
        const float* src = fa + ((size_t)cid << 16);      // cid*128*512
        float*       dst = out + ((size_t)cid << 17);     // cid*128*1024
        u16*         ad  = Ab + ((size_t)cid << 16);
        #pragma unroll 2
        for (int it = 0; it < 16; ++it) {
            int flat = it * 512 + tid;
            int row = flat >> 6, c8 = (flat & 63) << 3;
            const float* s = src + ((size_t)row << 9) + c8;
            f32x4 v0 = *(const f32x4*)s;
            f32x4 v1 = *(const f32x4*)(s + 4);
            float* d = dst + ((size_t)row << 10) + c8;
            *(f32x4*)d = v0;
            *(f32x4*)(d + 4) = v1;
            *(bf16x8*)(ad + ((size_t)row << 9) + c8) = cvt8(v0, v1);
        }
        const float* srcb = fb + ((size_t)cid << 16);
        u16*         bd   = Bb + ((size_t)cid << 16);
        #pragma unroll 2
        for (int it = 0; it < 16; ++it) {
            int flat = it * 512 + tid;
            int row = flat >> 6, c8 = (flat & 63) << 3;
            const float* s = srcb + ((size_t)row << 9) + c8;
            f32x4 v0 = *(const f32x4*)s;
            f32x4 v1 = *(const f32x4*)(s + 4);
            *(bf16x8*)(bd + ((size_t)row << 9) + c8) = cvt8(v0, v1);
        }
    }
}

// ---------------------------------------------------------------------------
// C = A @ BT^T, both bf16 via GLDS16. BM=128, BN=256, BK=32.
// 4 waves, wave tile 64x128 (mf=4, nf=8): 12 ds_read_b128 / 32 MFMA per step.
// Quad-XOR swizzle (physq = q ^ (row&3)) applied on SOURCE (stage) and READ.
// m248 2-phase: STAGE(t+1) before compute, one vmcnt(0)+barrier per K-step.
// FUSED: bias+relu Q[idx]-gather epilogue writes out[:,512+n0 .. +256).
// ---------------------------------------------------------------------------
template<bool FUSED>
__global__ __launch_bounds__(256, 1) void gemm_kernel(
    const u16* __restrict__ A, const u16* __restrict__ BT,
    u16* __restrict__ C, const int* __restrict__ idxb,
    const float* __restrict__ wb, const float* __restrict__ bias,
    const u16* __restrict__ Qb, float* __restrict__ out) {

    __shared__ __align__(16) char smem[FUSED ? 66560 : 49152];

    const int tid  = threadIdx.x;
    const int lane = tid & 63;
    const int wave = tid >> 6;
    const int m0   = blockIdx.x * 128;
    const int n0   = blockIdx.y * 256;
    const int l15  = lane & 15;
    const int fq   = lane >> 4;              // frag quad 0..3
    const int wr   = (wave >> 1) * 64;       // wave m-offset
    const int wc   = (wave & 1) * 128;       // wave n-offset

    // staging descriptors (source pre-swizzled; LDS dest linear)
    int aflat[2]; const u16* asp[2];
    #pragma unroll
    for (int i = 0; i < 2; ++i) {
        int flat = i * 256 + tid;            // 16B slot in A tile
        int row = flat >> 2, pq = flat & 3;
        aflat[i] = flat;
        asp[i] = A + (size_t)(m0 + row) * DD + ((pq ^ (row & 3)) << 3);
    }
    int bflat[4]; const u16* bsp[4];
    #pragma unroll
    for (int i = 0; i < 4; ++i) {
        int flat = i * 256 + tid;            // 16B slot in B tile
        int row = flat >> 2, pq = flat & 3;
        bflat[i] = flat;
        bsp[i] = BT + (size_t)(n0 + row) * DD + ((pq ^ (row & 3)) << 3);
    }

    // frag LDS byte offsets (swizzled read)
    int aoff[4], boff[8];
    #pragma unroll
    for (int mf = 0; mf < 4; ++mf) {
        int R = wr + mf * 16 + l15;
        aoff[mf] = R * 64 + ((fq ^ (R & 3)) << 4);
    }
    #pragma unroll
    for (int nf = 0; nf < 8; ++nf) {
        int R = wc + nf * 16 + l15;
        boff[nf] = 8192 + R * 64 + ((fq ^ (R & 3)) << 4);
    }

    f32x4 acc[4][8];
    #pragma unroll
    for (int mf = 0; mf < 4; ++mf)
        #pragma unroll
        for (int nf = 0; nf < 8; ++nf)
            acc[mf][nf] = (f32x4){0.f, 0.f, 0.f, 0.f};

#define STAGE(kk, bufb)                                                      \
    { _Pragma("unroll") for (int i = 0; i < 2; ++i)                          \
          GLDS16(asp[i] + (kk), smem + (bufb) + aflat[i] * 16);              \
      _Pragma("unroll") for (int i = 0; i < 4; ++i)                          \
          GLDS16(bsp[i] + (kk), smem + (bufb) + 8192 + bflat[i] * 16); }

    STAGE(0, 0);
    asm volatile("s_waitcnt vmcnt(0)" ::: "memory");
    __builtin_amdgcn_s_barrier();

    #pragma unroll 1
    for (int t = 0; t < 16; ++t) {
        const int cur = (t & 1) * 24576;
        if (t < 15) STAGE((t + 1) * 32, 24576 - cur);

        bf16x8 af[4], bfr[8];
        #pragma unroll
        for (int mf = 0; mf < 4; ++mf)
            af[mf] = *(const bf16x8*)(smem + cur + aoff[mf]);
        #pragma unroll
        for (int nf = 0; nf < 8; ++nf)
            bfr[nf] = *(const bf16x8*)(smem + cur + boff[nf]);
        #pragma unroll
        for (int mf = 0; mf < 4; ++mf)
            #pragma unroll
            for (int nf = 0; nf < 8; ++nf)
                acc[mf][nf] = __builtin_amdgcn_mfma_f32_16x16x32_bf16(
                    af[mf], bfr[nf], acc[mf][nf], 0, 0, 0);

        asm volatile("s_waitcnt vmcnt(0)" ::: "memory");
        __builtin_amdgcn_s_barrier();
    }

    const int r4 = (lane >> 4) * 4;

    if (!FUSED) {
        #pragma unroll
        for (int mf = 0; mf < 4; ++mf)
            #pragma unroll
            for (int nf = 0; nf < 8; ++nf)
                #pragma unroll
                for (int j = 0; j < 4; ++j) {
                    int row = m0 + wr + mf * 16 + r4 + j;
                    int col = n0 + wc + nf * 16 + l15;
                    C[(size_t)row * DD + col] = f2b_hw(acc[mf][nf][j]);
                }
        return;
    }

    // ---- fused epilogue: P' = acc + bias -> Ps (bf16), gather Q[idx] ----
    float bi[8];
    #pragma unroll
    for (int nf = 0; nf < 8; ++nf)
        bi[nf] = bias[n0 + wc + nf * 16 + l15];

    u16* Ps = (u16*)smem;                    // [128][260] bf16, 66560 B
    #pragma unroll
    for (int mf = 0; mf < 4; ++mf)
        #pragma unroll
        for (int nf = 0; nf < 8; ++nf)
            #pragma unroll
            for (int j = 0; j < 4; ++j)
                Ps[(wr + mf * 16 + r4 + j) * 260 + wc + nf * 16 + l15] =
                    f2b_hw(acc[mf][nf][j] + bi[nf]);
    __syncthreads();

    const int g16 = tid >> 4, l16 = tid & 15;
    const u16* qs = Qb + ((size_t)(m0 >> 11) << 20);   // batch * 2048 * 512
    #pragma unroll
    for (int k = 0; k < 8; ++k) {
        const int r  = g16 * 8 + k;
        const int gr = m0 + r;
        int4  iv = *(const int4*)(idxb + (size_t)gr * 4);
        f32x4 wv = *(const f32x4*)(wb + (size_t)gr * 4);
        #pragma unroll
        for (int cc = 0; cc < 2; ++cc) {
            const int col = cc * 128 + l16 * 8;        // 0..255 local
            bf16x8 p8 = *(const bf16x8*)(Ps + r * 260 + col);
            bf16x8 q0 = *(const bf16x8*)(qs + (size_t)iv.x * DD + n0 + col);
            bf16x8 q1 = *(const bf16x8*)(qs + (size_t)iv.y * DD + n0 + col);
            bf16x8 q2 = *(const bf16x8*)(qs + (size_t)iv.z * DD + n0 + col);
            bf16x8 q3 = *(const bf16x8*)(qs + (size_t)iv.w * DD + n0 + col);
            float o[8];
            #pragma unroll
            for (int j = 0; j < 8; ++j) {
                float p = b2f((u16)p8[j]);
                float s;
                s  = fmaxf(p + b2f((u16)q0[j]), 0.f) * wv[0];
                s += fmaxf(p + b2f((u16)q1[j]), 0.f) * wv[1];
                s += fmaxf(p + b2f((u16)q2[j]), 0.f) * wv[2];
                s += fmaxf(p + b2f((u16)q3[j]), 0.f) * wv[3];
                o[j] = s;
            }
            float* op = out + (size_t)gr * 1024 + 512 + n0 + col;
            *(f32x4*)op       = (f32x4){o[0], o[1], o[2], o[3]};
            *(f32x4*)(op + 4) = (f32x4){o[4], o[5], o[6], o[7]};
        }
    }
}

extern "C" void kernel_launch(void* const* d_in, const int* in_sizes, int n_in,
                              void* d_out, int out_size, void* d_ws, size_t ws_size,
                              hipStream_t stream) {
    const float* fa   = (const float*)d_in[0];
    const float* fb   = (const float*)d_in[1];
    const float* W    = (const float*)d_in[2];
    const float* bias = (const float*)d_in[3];
    const int*   ca   = (const int*)d_in[4];
    const int*   cb   = (const int*)d_in[5];
    float* out = (float*)d_out;

    char* ws = (char*)d_ws;
    u16*   Qb   = (u16*)(ws);                       // 32 MB bf16 Q
    u16*   Ab   = (u16*)(ws + 33554432);            // 32 MB bf16 fa
    u16*   Bb   = (u16*)(ws + 67108864);            // 32 MB bf16 fb
    u16*   W2T  = (u16*)(ws + 100663296);           // 512 KB
    u16*   WdT  = (u16*)(ws + 101187584);           // 512 KB
    int*   idxb = (int*)(ws + 101711872);           // 512 KB
    float* wb   = (float*)(ws + 102236160);         // 512 KB

    dim3 pg(8, 8);
    prep_w<<<pg, 256, 0, stream>>>(W, W2T, WdT);

    dim3 tg(16, 16);
    topk_kernel<<<tg, 512, 0, stream>>>(ca, cb, idxb, wb, fa, fb, Ab, Bb, out);

    dim3 gg(256, 2);
    gemm_kernel<false><<<gg, 256, 0, stream>>>(Bb, WdT, Qb, nullptr, nullptr,
                                               nullptr, nullptr, nullptr);
    gemm_kernel<true><<<gg, 256, 0, stream>>>(Ab, W2T, nullptr, idxb, wb,
                                              bias, Qb, out);
}